// Round 8
// baseline (130.560 us; speedup 1.0000x reference)
//
#include <hip/hip_runtime.h>

// inputs (256,128,64) f32, mask (256,128) i32, qparams (4,2,10) f32,
// W (4,256,10) f32, b (4,256) f32.
// out f32: outputs(256,128,256) ++ hx(128,256) ++ cx(128,256).
#define T_LEN 256
#define BATCH 128
#define NQ 10
#define HID 256
#define OUT_HX (T_LEN * BATCH * HID)
#define OUT_CX (OUT_HX + BATCH * HID)
#define ZSTRIDE 48          // z row: 4 gates x 12 (10 used, float4-aligned)
#define TC 64               // t-chunk
#define NCH 64              // chains per block

// ---------------------------------------------------------------------------
// K1: analytic circuit z for each (t,b,g) -> zg[(b*256+t)*48 + g*12 + w].
// DP validated (== exact statevector sim r3/r4; passing since r6).
// ---------------------------------------------------------------------------
__global__ __launch_bounds__(256) void zcalc_kernel(
    const float* __restrict__ x, const float* __restrict__ qp,
    float* __restrict__ zg)
{
  const int flat = blockIdx.x * 256 + threadIdx.x;   // (t*128+b)*4+g
  const int g = flat & 3, tb = flat >> 2;
  const int t = tb >> 7, b = tb & 127;

  float cphi[NQ], sphi[NQ], cth[NQ], sth[NQ];
#pragma unroll
  for (int k = 0; k < NQ; ++k) {
    float ang = x[tb * 64 + k] + qp[g * 20 + k];
    sphi[k] = __sinf(ang);  cphi[k] = __cosf(ang);
    float t1 = qp[g * 20 + 10 + k];
    sth[k] = __sinf(t1);    cth[k] = __cosf(t1);
  }
  float* zp = zg + (b * T_LEN + t) * ZSTRIDE + g * 12;
#pragma unroll
  for (int w = 0; w < NQ; ++w) {
    float vI, vZ, vY, vX; int js;
    if (w == NQ - 1) { vI = 0.f; vZ = cth[NQ-1]; vY = sth[NQ-1]; vX = 0.f; js = NQ - 2; }
    else             { vI = 1.f; vZ = 0.f; vY = 0.f; vX = 0.f; js = w; }
#pragma unroll
    for (int j = js; j >= 0; --j) {
      float nI = cth[j] * (cphi[j+1] * vZ - sphi[j+1] * vY);
      float nZ = cth[j] * vI;
      float nY = sth[j] * vX;
      float nX = -sth[j] * (sphi[j+1] * vZ + cphi[j+1] * vY);
      vI = nI; vZ = nZ; vY = nY; vX = nX;
    }
    zp[w] = vI + cphi[0] * vZ - sphi[0] * vY;
  }
}

// ---------------------------------------------------------------------------
// K2: chunked scan. Block=(b, h-quarter): 64 chains x 4 gate-lanes.
// Per chunk: [stage z | barrier | scan 64 steps (c + raw pre3 -> LDS) |
//            barrier | parallel h=o*tanh(c) + stores].
// ---------------------------------------------------------------------------
__global__ __launch_bounds__(256) void scan_kernel(
    const float* __restrict__ zg, const int* __restrict__ mask,
    const float* __restrict__ W, const float* __restrict__ bias,
    float* __restrict__ out)
{
  const int b   = blockIdx.x;         // 0..127
  const int hq  = blockIdx.y;         // 0..3
  const int tid = threadIdx.x;        // 0..255
  const int g   = tid & 3;
  const int ch  = tid >> 2;           // 0..63
  const int h   = hq * 64 + ch;

  __shared__ __align__(16) float zs[TC][ZSTRIDE];   // 12 KB
  __shared__ float cbuf[TC][NCH + 1];               // 16.25 KB
  __shared__ float p3buf[TC][NCH + 1];              // 16.25 KB
  __shared__ float mk[T_LEN];                       // 1 KB

  float Wreg[NQ];
#pragma unroll
  for (int n = 0; n < NQ; ++n) Wreg[n] = W[(g * HID + h) * NQ + n];
  const float bg = bias[g * HID + h];

  for (int t0 = tid; t0 < T_LEN; t0 += 256) mk[t0] = (float)mask[t0 * BATCH + b];

  // uniform gate constants: val = m*(a*sigma(scale*pre)+bt) + d*(1-m)
  const float scale_in = (g == 2) ? -2.f : -1.f;
  const float a_c  = (g == 2) ? 2.f : 1.f;
  const float bt_c = (g == 2) ? -1.f : 0.f;
  const float d_c  = (g == 0) ? 1.f : 0.f;    // o-gate's mask applied in phase C

  float c = 0.f;
  const float4* zsrc = (const float4*)(zg + b * T_LEN * ZSTRIDE);
  const int g12 = g * 12;

  for (int ck = 0; ck < T_LEN / TC; ++ck) {
    const int tt = ck * TC;
    // stage z chunk: 64*48 floats = 768 float4 / 256 threads
    {
      float4* dst = (float4*)&zs[0][0];
#pragma unroll
      for (int i = 0; i < 3; ++i)
        dst[i * 256 + tid] = zsrc[tt * (ZSTRIDE / 4) + i * 256 + tid];
    }
    __syncthreads();

#pragma unroll 8
    for (int s = 0; s < TC; ++s) {
      float4 za = *(const float4*)&zs[s][g12];
      float4 zb = *(const float4*)&zs[s][g12 + 4];
      float2 zc = *(const float2*)&zs[s][g12 + 8];
      float acc0 = fmaf(za.x, Wreg[0], bg);
      acc0 = fmaf(za.y, Wreg[1], acc0);
      acc0 = fmaf(za.z, Wreg[2], acc0);
      acc0 = fmaf(za.w, Wreg[3], acc0);
      acc0 = fmaf(zc.x, Wreg[8], acc0);
      float acc1 = zb.x * Wreg[4];
      acc1 = fmaf(zb.y, Wreg[5], acc1);
      acc1 = fmaf(zb.z, Wreg[6], acc1);
      acc1 = fmaf(zb.w, Wreg[7], acc1);
      acc1 = fmaf(zc.y, Wreg[9], acc1);
      float pre = acc0 + acc1;
      if (g == 3) p3buf[s][ch] = pre;          // raw o-preact, sigma deferred
      float m = mk[tt + s];
      float e = __expf(scale_in * pre);
      float u = __builtin_amdgcn_rcpf(1.f + e);
      float val = fmaf(m, fmaf(a_c, u, bt_c), d_c * (1.f - m));
      float v1 = __shfl_xor(val, 1, 64);       // g0 <- i
      float v2 = __shfl_xor(val, 2, 64);       // g0 <- gbar
      if (g == 0) {
        c = fmaf(val, c, v1 * v2);
        cbuf[s][ch] = c;
      }
    }
    __syncthreads();

    // phase C: h_t = (m*sigma(pre3)+(1-m)) * tanh(c_t), fully parallel
#pragma unroll
    for (int i = 0; i < 16; ++i) {
      int p = i * 256 + tid;                   // 4096 = 64t x 64ch
      int lt = p >> 6, lch = p & 63;
      int t = tt + lt;
      float cv = cbuf[lt][lch];
      float p3 = p3buf[lt][lch];
      float m = mk[t];
      float eo = __expf(-p3);
      float o  = fmaf(m, __builtin_amdgcn_rcpf(1.f + eo), 1.f - m);
      float e2 = __expf(-2.f * cv);
      float tc2 = fmaf(2.f, __builtin_amdgcn_rcpf(1.f + e2), -1.f);
      float hv = o * tc2;
      out[t * (BATCH * HID) + b * HID + hq * 64 + lch] = hv;
      if (t == T_LEN - 1) out[OUT_HX + b * HID + hq * 64 + lch] = hv;
    }
    // no barrier needed: next z-stage touches only zs (scan-complete per the
    // post-scan barrier); cbuf/p3buf rewritten only after next pre-scan barrier
  }
  if (g == 0) out[OUT_CX + b * HID + h] = c;
}

extern "C" void kernel_launch(void* const* d_in, const int* in_sizes, int n_in,
                              void* d_out, int out_size, void* d_ws, size_t ws_size,
                              hipStream_t stream)
{
  // identify arrays by unique element counts (order-proof)
  int ii = 0, im = 1, iq = 2, iw = 3, ib = 4;
  for (int i = 0; i < n_in; ++i) {
    switch (in_sizes[i]) {
      case 2097152: ii = i; break;   // inputs (256,128,64)
      case 32768:   im = i; break;   // mask (256,128)
      case 80:      iq = i; break;   // qparams (4,2,10)
      case 10240:   iw = i; break;   // W (4,256,10)
      case 1024:    ib = i; break;   // b (4,256)
      default: break;
    }
  }
  const float* inputs  = (const float*)d_in[ii];
  const int*   mask    = (const int*)d_in[im];
  const float* qparams = (const float*)d_in[iq];
  const float* W       = (const float*)d_in[iw];
  const float* bias    = (const float*)d_in[ib];
  float*       out     = (float*)d_out;

  float* zg = (float*)d_ws;   // 128*256*48*4 = 6.3 MB

  zcalc_kernel<<<dim3(T_LEN * BATCH * 4 / 256), dim3(256), 0, stream>>>(
      inputs, qparams, zg);
  scan_kernel<<<dim3(BATCH, 4), dim3(256), 0, stream>>>(
      zg, mask, W, bias, out);
}